// Round 1
// baseline (255.784 us; speedup 1.0000x reference)
//
#include <hip/hip_runtime.h>
#include <stdint.h>

#define B_ 2
#define S_ 2048
#define D_ 1024
#define H_ 16
#define HD_ 64
#define M_TOT (B_*S_)   // 4096

typedef __bf16 bf16;
typedef bf16 bf16x8 __attribute__((ext_vector_type(8)));
typedef float f32x4 __attribute__((ext_vector_type(4)));

__device__ __forceinline__ void gload_lds16(const void* g, void* l) {
    __builtin_amdgcn_global_load_lds((const __attribute__((address_space(1))) void*)g,
                                     (__attribute__((address_space(3))) void*)l, 16, 0, 0);
}

// ---------------- f32 -> bf16 convert ----------------
__global__ __launch_bounds__(256) void cvt_kernel(
    const float* __restrict__ q, const float* __restrict__ k, const float* __restrict__ v,
    const float* __restrict__ wq, const float* __restrict__ wk,
    const float* __restrict__ wv, const float* __restrict__ wo,
    bf16* __restrict__ xq, bf16* __restrict__ xk, bf16* __restrict__ xv,
    bf16* __restrict__ wqb, bf16* __restrict__ wkb, bf16* __restrict__ wvb, bf16* __restrict__ wob)
{
    const float* src; bf16* dst; int n;
    switch (blockIdx.y) {
        case 0: src=q;  dst=xq;  n=M_TOT*D_; break;
        case 1: src=k;  dst=xk;  n=M_TOT*D_; break;
        case 2: src=v;  dst=xv;  n=M_TOT*D_; break;
        case 3: src=wq; dst=wqb; n=D_*D_;    break;
        case 4: src=wk; dst=wkb; n=D_*D_;    break;
        case 5: src=wv; dst=wvb; n=D_*D_;    break;
        default: src=wo; dst=wob; n=D_*D_;   break;
    }
    int i = (blockIdx.x*blockDim.x + threadIdx.x)*8;
    if (i >= n) return;
    const f32x4* s4 = (const f32x4*)(src + i);
    f32x4 a = s4[0], b = s4[1];
    bf16x8 o;
    #pragma unroll
    for (int j = 0; j < 4; ++j) { o[j] = (bf16)a[j]; o[j+4] = (bf16)b[j]; }
    *(bf16x8*)(dst + i) = o;
}

// ---------------- GEMM mainloop: C[128,128] = A[128,K] * W[128,K]^T ----------------
// A row-major (M,K) bf16, W row-major (N,K) bf16 (torch Linear weight). 256 thr, 4 waves 2x2.
__device__ __forceinline__ void gemm_mainloop(const bf16* __restrict__ A, const bf16* __restrict__ Wt,
                                              int brow, int bcol, bf16* As, bf16* Bs,
                                              f32x4 (&acc)[4][4])
{
    const int tid = threadIdx.x;
    const int l = tid & 63, w = tid >> 6;
    const int wr = w >> 1, wc = w & 1;
    const int lr = l & 15, lq = l >> 4;

    for (int k0 = 0; k0 < D_; k0 += 32) {
        #pragma unroll
        for (int i = 0; i < 2; ++i) {
            int id = i*256 + tid;
            int row = id >> 2, c8 = (id & 3) << 3;
            gload_lds16(A  + (size_t)(brow + row)*D_ + k0 + c8, As + id*8);
            gload_lds16(Wt + (size_t)(bcol + row)*D_ + k0 + c8, Bs + id*8);
        }
        __syncthreads();
        bf16x8 af[4], bf[4];
        #pragma unroll
        for (int m = 0; m < 4; ++m)
            af[m] = *(const bf16x8*)&As[(wr*64 + m*16 + lr)*32 + lq*8];
        #pragma unroll
        for (int n = 0; n < 4; ++n)
            bf[n] = *(const bf16x8*)&Bs[(wc*64 + n*16 + lr)*32 + lq*8];
        #pragma unroll
        for (int m = 0; m < 4; ++m)
            #pragma unroll
            for (int n = 0; n < 4; ++n)
                acc[m][n] = __builtin_amdgcn_mfma_f32_16x16x32_bf16(af[m], bf[n], acc[m][n], 0, 0, 0);
        __syncthreads();
    }
}

// ---------------- QKV projection GEMM (z: 0=Q,1=K,2=V) ----------------
__global__ __launch_bounds__(256) void gemm_qkv(
    const bf16* __restrict__ xq, const bf16* __restrict__ xk, const bf16* __restrict__ xv,
    const bf16* __restrict__ wqb, const bf16* __restrict__ wkb, const bf16* __restrict__ wvb,
    const float* __restrict__ bq, const float* __restrict__ bk, const float* __restrict__ bv,
    bf16* __restrict__ Qh, bf16* __restrict__ Kh, bf16* __restrict__ Vt)
{
    __shared__ __align__(16) bf16 As[128*32];
    __shared__ __align__(16) bf16 Bs[128*32];
    const int z = blockIdx.z;
    const bf16* A  = (z==0) ? xq  : (z==1) ? xk  : xv;
    const bf16* Wt = (z==0) ? wqb : (z==1) ? wkb : wvb;
    const float* bias = (z==0) ? bq : (z==1) ? bk : bv;

    const int brow = (blockIdx.x & 31)*128;
    const int bcol = (blockIdx.x >> 5)*128;

    f32x4 acc[4][4] = {};
    gemm_mainloop(A, Wt, brow, bcol, As, Bs, acc);

    const int tid = threadIdx.x;
    const int l = tid & 63, w = tid >> 6;
    const int wr = w >> 1, wc = w & 1;
    const int lr = l & 15, lq = l >> 4;

    #pragma unroll
    for (int m = 0; m < 4; ++m)
        #pragma unroll
        for (int n = 0; n < 4; ++n) {
            int col = bcol + wc*64 + n*16 + lr;
            float bv_ = bias[col];
            int h = col >> 6, hd = col & 63;
            #pragma unroll
            for (int r = 0; r < 4; ++r) {
                int row = brow + wr*64 + m*16 + lq*4 + r;
                int b = row >> 11, s = row & 2047;
                float val = acc[m][n][r] + bv_;
                if (z < 2) {
                    bf16* dst = (z==0) ? Qh : Kh;
                    dst[(((size_t)b*H_ + h)*S_ + s)*HD_ + hd] = (bf16)val;
                } else {
                    Vt[(((size_t)b*H_ + h)*HD_ + hd)*S_ + s] = (bf16)val;
                }
            }
        }
}

// ---------------- output projection GEMM ----------------
__global__ __launch_bounds__(256) void gemm_out(
    const bf16* __restrict__ Oat, const bf16* __restrict__ wob,
    const float* __restrict__ bo, float* __restrict__ out)
{
    __shared__ __align__(16) bf16 As[128*32];
    __shared__ __align__(16) bf16 Bs[128*32];
    const int brow = (blockIdx.x & 31)*128;
    const int bcol = (blockIdx.x >> 5)*128;

    f32x4 acc[4][4] = {};
    gemm_mainloop(Oat, wob, brow, bcol, As, Bs, acc);

    const int tid = threadIdx.x;
    const int l = tid & 63, w = tid >> 6;
    const int wr = w >> 1, wc = w & 1;
    const int lr = l & 15, lq = l >> 4;

    #pragma unroll
    for (int m = 0; m < 4; ++m)
        #pragma unroll
        for (int n = 0; n < 4; ++n) {
            int col = bcol + wc*64 + n*16 + lr;
            float bv_ = bo[col];
            #pragma unroll
            for (int r = 0; r < 4; ++r) {
                int row = brow + wr*64 + m*16 + lq*4 + r;
                out[(size_t)row*D_ + col] = acc[m][n][r] + bv_;
            }
        }
}

// ---------------- causal flash attention ----------------
// grid (S/128, B*H), 256 thr = 4 waves; wave w owns q-rows [qtile*128 + w*32, +32)
__global__ __launch_bounds__(256) void attn_kernel(
    const bf16* __restrict__ Qh, const bf16* __restrict__ Kh,
    const bf16* __restrict__ Vt, bf16* __restrict__ Oat)
{
    __shared__ __align__(16) bf16 Pl[4][32*32];
    const int tid = threadIdx.x;
    const int l = tid & 63, w = tid >> 6;
    const int lr = l & 15, lq = l >> 4;
    const int bh = blockIdx.y;
    const int b = bh >> 4, h = bh & 15;
    const int q0 = blockIdx.x*128 + w*32;

    const bf16* Qp = Qh + (size_t)bh * S_ * HD_;
    const bf16* Kp = Kh + (size_t)bh * S_ * HD_;
    const bf16* Vp = Vt + (size_t)bh * HD_ * S_;

    // Q fragments (A-layout): row = q0+m*16+lr, k = ks*32 + lq*8
    bf16x8 aq[2][2];
    #pragma unroll
    for (int m = 0; m < 2; ++m)
        #pragma unroll
        for (int ks = 0; ks < 2; ++ks)
            aq[m][ks] = *(const bf16x8*)&Qp[(size_t)(q0 + m*16 + lr)*HD_ + ks*32 + lq*8];

    f32x4 o[2][4] = {};
    float mrun[2][4], lrun[2][4];
    #pragma unroll
    for (int m = 0; m < 2; ++m)
        #pragma unroll
        for (int r = 0; r < 4; ++r) { mrun[m][r] = -1e30f; lrun[m][r] = 0.f; }

    const float sc = 0.125f * 1.44269504f;   // 1/sqrt(64) * log2(e)
    const int nkt = (q0 >> 5) + 1;

    for (int kt = 0; kt < nkt; ++kt) {
        const int kc0 = kt*32;
        // K fragments (B-layout): col = kc0+n*16+lr, k = ks*32+lq*8
        bf16x8 bk[2][2];
        #pragma unroll
        for (int n = 0; n < 2; ++n)
            #pragma unroll
            for (int ks = 0; ks < 2; ++ks)
                bk[n][ks] = *(const bf16x8*)&Kp[(size_t)(kc0 + n*16 + lr)*HD_ + ks*32 + lq*8];

        f32x4 s[2][2] = {};
        #pragma unroll
        for (int m = 0; m < 2; ++m)
            #pragma unroll
            for (int n = 0; n < 2; ++n)
                #pragma unroll
                for (int ks = 0; ks < 2; ++ks)
                    s[m][n] = __builtin_amdgcn_mfma_f32_16x16x32_bf16(aq[m][ks], bk[n][ks], s[m][n], 0, 0, 0);

        float p[2][2][4];
        #pragma unroll
        for (int m = 0; m < 2; ++m)
            #pragma unroll
            for (int r = 0; r < 4; ++r) {
                const int qrow = q0 + m*16 + lq*4 + r;
                #pragma unroll
                for (int n = 0; n < 2; ++n) {
                    float v = s[m][n][r] * sc;
                    if (kc0 + n*16 + lr > qrow) v = -1e30f;   // causal mask (log2 domain)
                    s[m][n][r] = v;
                }
            }
        #pragma unroll
        for (int m = 0; m < 2; ++m)
            #pragma unroll
            for (int r = 0; r < 4; ++r) {
                float vmax = fmaxf(s[m][0][r], s[m][1][r]);
                vmax = fmaxf(vmax, __shfl_xor(vmax, 1, 16));
                vmax = fmaxf(vmax, __shfl_xor(vmax, 2, 16));
                vmax = fmaxf(vmax, __shfl_xor(vmax, 4, 16));
                vmax = fmaxf(vmax, __shfl_xor(vmax, 8, 16));
                float nm = fmaxf(mrun[m][r], vmax);
                float alpha = exp2f(mrun[m][r] - nm);
                mrun[m][r] = nm;
                float psum = 0.f;
                #pragma unroll
                for (int n = 0; n < 2; ++n) {
                    float pv = exp2f(s[m][n][r] - nm);
                    p[m][n][r] = pv; psum += pv;
                }
                psum += __shfl_xor(psum, 1, 16);
                psum += __shfl_xor(psum, 2, 16);
                psum += __shfl_xor(psum, 4, 16);
                psum += __shfl_xor(psum, 8, 16);
                lrun[m][r] = lrun[m][r]*alpha + psum;
                #pragma unroll
                for (int n4 = 0; n4 < 4; ++n4) o[m][n4][r] *= alpha;
            }
        // P: C-layout -> LDS -> A-layout (per-wave private buffer; DS ops in-order per wave)
        #pragma unroll
        for (int m = 0; m < 2; ++m)
            #pragma unroll
            for (int n = 0; n < 2; ++n)
                #pragma unroll
                for (int r = 0; r < 4; ++r)
                    Pl[w][(m*16 + lq*4 + r)*32 + n*16 + lr] = (bf16)p[m][n][r];
        bf16x8 pa[2];
        #pragma unroll
        for (int m = 0; m < 2; ++m)
            pa[m] = *(const bf16x8*)&Pl[w][(m*16 + lr)*32 + lq*8];
        // V fragments (B-layout from transposed V): k = kc0+lq*8+j, col(hd) = n*16+lr
        bf16x8 bv[4];
        #pragma unroll
        for (int n = 0; n < 4; ++n)
            bv[n] = *(const bf16x8*)&Vp[(size_t)(n*16 + lr)*S_ + kc0 + lq*8];
        #pragma unroll
        for (int m = 0; m < 2; ++m)
            #pragma unroll
            for (int n = 0; n < 4; ++n)
                o[m][n] = __builtin_amdgcn_mfma_f32_16x16x32_bf16(pa[m], bv[n], o[m][n], 0, 0, 0);
    }

    // epilogue: O / l  -> (B,S,D) bf16
    #pragma unroll
    for (int m = 0; m < 2; ++m)
        #pragma unroll
        for (int n = 0; n < 4; ++n) {
            int col = h*64 + n*16 + lr;
            #pragma unroll
            for (int r = 0; r < 4; ++r) {
                int qrow = q0 + m*16 + lq*4 + r;
                float val = o[m][n][r] / lrun[m][r];
                Oat[((size_t)b*S_ + qrow)*D_ + col] = (bf16)val;
            }
        }
}

extern "C" void kernel_launch(void* const* d_in, const int* in_sizes, int n_in,
                              void* d_out, int out_size, void* d_ws, size_t ws_size,
                              hipStream_t stream) {
    const float* q  = (const float*)d_in[0];
    const float* k  = (const float*)d_in[1];
    const float* v  = (const float*)d_in[2];
    // d_in[3] = mask (causal, hard-coded in attn kernel)
    const float* wq = (const float*)d_in[4];
    const float* bq = (const float*)d_in[5];
    const float* wk = (const float*)d_in[6];
    const float* bk = (const float*)d_in[7];
    const float* wv = (const float*)d_in[8];
    const float* bv = (const float*)d_in[9];
    const float* wo = (const float*)d_in[10];
    const float* bo = (const float*)d_in[11];
    float* out = (float*)d_out;

    char* p = (char*)d_ws;
    const size_t XSZ = (size_t)M_TOT*D_*sizeof(bf16);   // 8 MiB
    const size_t WSZ = (size_t)D_*D_*sizeof(bf16);      // 2 MiB
    bf16* xq  = (bf16*)p; p += XSZ;
    bf16* xk  = (bf16*)p; p += XSZ;
    bf16* xv  = (bf16*)p; p += XSZ;
    bf16* wqb = (bf16*)p; p += WSZ;
    bf16* wkb = (bf16*)p; p += WSZ;
    bf16* wvb = (bf16*)p; p += WSZ;
    bf16* wob = (bf16*)p; p += WSZ;
    bf16* Qh  = (bf16*)p; p += XSZ;
    bf16* Kh  = (bf16*)p; p += XSZ;
    bf16* Vt  = (bf16*)p; p += XSZ;
    bf16* Oat = (bf16*)p; p += XSZ;

    cvt_kernel<<<dim3(2048, 7), 256, 0, stream>>>(q, k, v, wq, wk, wv, wo,
                                                  xq, xk, xv, wqb, wkb, wvb, wob);
    gemm_qkv<<<dim3(256, 1, 3), 256, 0, stream>>>(xq, xk, xv, wqb, wkb, wvb,
                                                  bq, bk, bv, Qh, Kh, Vt);
    attn_kernel<<<dim3(S_/128, B_*H_), 256, 0, stream>>>(Qh, Kh, Vt, Oat);
    gemm_out<<<dim3(256), 256, 0, stream>>>(Oat, wob, bo, out);
}